// Round 11
// baseline (1931.278 us; speedup 1.0000x reference)
//
#include <hip/hip_runtime.h>
#include <stdint.h>

// ============================================================================
// 24-qubit simulator, 9 fully-coalesced passes over 3 tile types.
// State SOA: re in d_out (2^24 f32), im in d_ws+WS_IM. Qubit q <-> bit 23-q.
// Tiles (13 bits, 8192 amps, 256 thr x 32 amps):
//   A: g bits 0..12          (qubits 11..23)  runs 32KiB   blk = bits 13..23
//   P: g bits {0..6,13..18}  (qubits 5..10)   runs 512B    blk = bits 7..12,19..23
//   Q: g bits {0..7,19..23}  (qubits 0..4)    runs 1KiB    blk = bits 8..18
// Schedule: A0 | Q0 | P0.ZZ0.P1 | Q1 | A1.ZZ1.A2 | Q2 | P2.ZZ2.P3 | Q3 | A3.ZZ3.scale
// ============================================================================

#define WS_NORM 0
#define WS_U    8     // 96 matrices * 8 floats
#define WS_W    1024  // 4 layers * 32: w[0..22], [23]=wrap, [24]=S
#define WS_IM   4096  // imag plane: 2^24 floats

__device__ __forceinline__ int swz(int i) { return i ^ ((i >> 5) & 31); }

__device__ __forceinline__ float2 cmul(float2 a, float2 b) {
  return make_float2(a.x * b.x - a.y * b.y, a.x * b.y + a.y * b.x);
}

template <int P>
__device__ __forceinline__ void gate(float2 c[32], float2 u00, float2 u01,
                                     float2 u10, float2 u11) {
#pragma unroll
  for (int m = 0; m < 16; ++m) {
    const int r0 = ((m >> P) << (P + 1)) | (m & ((1 << P) - 1));
    const int r1 = r0 | (1 << P);
    float2 a = c[r0], b = c[r1];
    float2 n0, n1;
    n0.x = u00.x * a.x - u00.y * a.y + u01.x * b.x - u01.y * b.y;
    n0.y = u00.x * a.y + u00.y * a.x + u01.x * b.y + u01.y * b.x;
    n1.x = u10.x * a.x - u10.y * a.y + u11.x * b.x - u11.y * b.y;
    n1.y = u10.x * a.y + u10.y * a.x + u11.x * b.y + u11.y * b.x;
    c[r0] = n0;
    c[r1] = n1;
  }
}

// ---------------------------------------------------------------------------
__global__ void setup_kernel(const float* __restrict__ Hre,
                             const float* __restrict__ Him,
                             const float* __restrict__ th1,
                             const float* __restrict__ th2, float* ws) {
  const int id = threadIdx.x;
  if (id < 96) {
    const int l = id / 24, q = id % 24;
    const float* hr = Hre + (l * 24 + q) * 4;
    const float* hi = Him + (l * 24 + q) * 4;
    const float h0 = hi[0] + hi[3];
    const float hz = hi[0] - hi[3];
    const float hx = hi[1] + hi[2];
    const float hy = hr[1] - hr[2];
    const float th = sqrtf(hx * hx + hy * hy + hz * hz);
    const float cth = cosf(th), sth = sinf(th);
    const float sc = (th > 1e-30f) ? sth / th : 1.0f;
    const float2 e = make_float2(cosf(h0), sinf(h0));
    const float2 u00 = cmul(e, make_float2(cth, sc * hz));
    const float2 u01 = cmul(e, make_float2(sc * hy, sc * hx));
    const float2 u10 = cmul(e, make_float2(-sc * hy, sc * hx));
    const float2 u11 = cmul(e, make_float2(cth, -sc * hz));
    float* p = ws + WS_U + (l * 24 + q) * 8;
    p[0] = u00.x; p[1] = u00.y; p[2] = u01.x; p[3] = u01.y;
    p[4] = u10.x; p[5] = u10.y; p[6] = u11.x; p[7] = u11.y;
  } else if (id < 100) {
    const int l = id - 96;
    float w[23];
    for (int k = 0; k < 23; ++k) w[k] = 0.f;
    for (int i = 0; i < 12; ++i) w[22 - 2 * i] += th1[l * 12 + i];
    for (int i = 0; i < 11; ++i) w[21 - 2 * i] += th2[l * 12 + i];
    const float wrap = th2[l * 12 + 11];
    float S = wrap;
    for (int k = 0; k < 23; ++k) S += w[k];
    float* p = ws + WS_W + l * 32;
    for (int k = 0; k < 23; ++k) p[k] = w[k];
    p[23] = wrap;
    p[24] = S;
  } else if (id == 100) {
    ws[WS_NORM] = 0.f;
  }
}

// ---------------------------------------------------------------------------
__device__ __forceinline__ uint32_t gA(uint32_t blk, uint32_t ti) {
  return (blk << 13) | ti;
}
__device__ __forceinline__ uint32_t gP(uint32_t blk, uint32_t ti) {
  return (ti & 0x7F) | ((ti >> 7) << 13) | ((blk & 0x3F) << 7) |
         ((blk >> 6) << 19);
}
__device__ __forceinline__ uint32_t gQ(uint32_t blk, uint32_t ti) {
  return (ti & 0xFF) | ((ti >> 8) << 19) | (blk << 8);
}

#define GATE(P, l, q)                                                      \
  {                                                                        \
    const float* up = wsU + ((l) * 24 + (q)) * 8;                          \
    gate<P>(c, make_float2(up[0], up[1]), make_float2(up[2], up[3]),       \
            make_float2(up[4], up[5]), make_float2(up[6], up[7]));         \
  }

#define XPOSE(CUR, NEW)                                   \
  __syncthreads();                                        \
  _Pragma("unroll") for (int r = 0; r < 32; ++r) {        \
    lds[swz(CUR)] = c[r];                                 \
  }                                                       \
  __syncthreads();                                        \
  _Pragma("unroll") for (int r = 0; r < 32; ++r) {        \
    c[r] = lds[swz(NEW)];                                 \
  }

#define IDX_L (t + (r << 8))
#define IDX_A ((t << 5) | r)
#define IDX_B ((t & 31) | (r << 5) | ((t >> 5) << 10))

// ---------------------------------------------------------------------------
// ZZ phase: phi(g) = S - 2*sum_k w[k]*y_k - 2*wrap*(b0^b23), y = g^(g>>1).
// TILE selects the r-varying window (which g-bits sit in register index r):
//   0 (A, arr B): r -> g5..9      window y4..9,    wrap fixed
//   1 (P, arr B): r -> g{5,6,13,14,15} window y{4,5,6,12..15}, wrap fixed
//   2 (Q, arr L): r -> g19..23    window y18..22,  wrap r-dependent (b23 in r)
// ---------------------------------------------------------------------------
template <int TILE>
__device__ __forceinline__ uint32_t zzspread(int r) {
  if constexpr (TILE == 0) return (uint32_t)r << 5;
  else if constexpr (TILE == 1)
    return ((uint32_t)(r & 3) << 5) | ((uint32_t)(r >> 2) << 13);
  else return (uint32_t)r << 19;
}

template <int TILE>
__device__ __forceinline__ void zz_apply(float2 c[32],
                                         const float* __restrict__ wsW,
                                         int layer, uint32_t gbase) {
  constexpr uint32_t WMASK = (TILE == 0) ? 0x3F0u
                           : (TILE == 1) ? ((7u << 4) | (0xFu << 12))
                                         : (0x1Fu << 18);
  constexpr bool WRAPR = (TILE == 2);
  const float* w = wsW + layer * 32;
  float w2[23];
#pragma unroll
  for (int k = 0; k < 23; ++k) w2[k] = 2.f * w[k];
  const float wrap2 = 2.f * w[23];
  const float S = w[24];
  const uint32_t y0 = gbase ^ (gbase >> 1);
  float phi_b = S;
#pragma unroll
  for (int k = 0; k < 23; ++k)
    if (!(WMASK & (1u << k))) phi_b -= w2[k] * (float)((y0 >> k) & 1);
  if (!WRAPR) phi_b -= wrap2 * (float)((gbase ^ (gbase >> 23)) & 1);
#pragma unroll
  for (int r = 0; r < 32; ++r) {
    const uint32_t g = gbase | zzspread<TILE>(r);
    const uint32_t y = g ^ (g >> 1);
    float phi = phi_b;
#pragma unroll
    for (int k = 0; k < 23; ++k)
      if (WMASK & (1u << k)) phi -= w2[k] * (float)((y >> k) & 1);
    if (WRAPR) phi -= wrap2 * (float)((g ^ (g >> 23)) & 1);
    float sn, cs;
    __sincosf(phi, &sn, &cs);
    c[r] = cmul(c[r], make_float2(cs, sn));
  }
}

// ---------------------------------------------------------------------------
// A-type pass (qubits 11..23). MODE 0: load input+norm, A_l, store.
// MODE 1: A_l, ZZ_l, A_{l+1}, store.  MODE 2: A_l, ZZ_l, scale, store re.
// ---------------------------------------------------------------------------
template <int MODE>
__global__ __launch_bounds__(256, 2) void qpassA(
    const float* __restrict__ in_re, const float* __restrict__ in_im,
    float* __restrict__ sre_st, float* __restrict__ sim_st,
    const float* __restrict__ ws, float* wsn, int layer) {
  __shared__ float2 lds[8192];
  const int t = threadIdx.x;
  const uint32_t blk = blockIdx.x;
  const float* wsU = ws + WS_U;
  float2 c[32];

#pragma unroll
  for (int r = 0; r < 32; ++r) {
    const uint32_t g = gA(blk, IDX_L);
    if (MODE == 0)
      c[r] = make_float2(in_re[g], in_im[g]);
    else
      c[r] = make_float2(sre_st[g], sim_st[g]);
  }

  if (MODE == 0) {
    float ss = 0.f;
#pragma unroll
    for (int r = 0; r < 32; ++r)
      ss = fmaf(c[r].x, c[r].x, fmaf(c[r].y, c[r].y, ss));
    for (int off = 32; off > 0; off >>= 1) ss += __shfl_down(ss, off);
    if ((t & 63) == 0) atomicAdd(wsn + WS_NORM, ss);
  }

  const int l0 = layer;
  GATE(0, l0, 15) GATE(1, l0, 14) GATE(2, l0, 13) GATE(3, l0, 12) GATE(4, l0, 11)
  XPOSE(IDX_L, IDX_A)
  GATE(0, l0, 23) GATE(1, l0, 22) GATE(2, l0, 21) GATE(3, l0, 20) GATE(4, l0, 19)
  XPOSE(IDX_A, IDX_B)
  GATE(0, l0, 18) GATE(1, l0, 17) GATE(2, l0, 16)

  if (MODE != 0) {
    const uint32_t ti0 = (t & 31) | ((t >> 5) << 10);
    zz_apply<0>(c, ws + WS_W, l0, gA(blk, ti0));
  }

  if (MODE == 1) {
    const int l1 = layer + 1;
    GATE(0, l1, 18) GATE(1, l1, 17) GATE(2, l1, 16) GATE(3, l1, 15) GATE(4, l1, 14)
    XPOSE(IDX_B, IDX_A)
    GATE(0, l1, 23) GATE(1, l1, 22) GATE(2, l1, 21) GATE(3, l1, 20) GATE(4, l1, 19)
    XPOSE(IDX_A, IDX_L)
    GATE(2, l1, 13) GATE(3, l1, 12) GATE(4, l1, 11)
#pragma unroll
    for (int r = 0; r < 32; ++r) {
      const uint32_t g = gA(blk, IDX_L);
      sre_st[g] = c[r].x;
      sim_st[g] = c[r].y;
    }
  } else {
    float scale = 1.f;
    if (MODE == 2) scale = rsqrtf(wsn[WS_NORM]);
#pragma unroll
    for (int r = 0; r < 32; ++r) {
      const uint32_t g = gA(blk, IDX_B);
      sre_st[g] = c[r].x * scale;
      if (MODE != 2) sim_st[g] = c[r].y;
    }
  }
}

// ---------------------------------------------------------------------------
// P-type pass (qubits 5..10): P_l, ZZ_l, P_{l+1}.
// arr L (r = ti8..12 -> g14..18 -> q9..5), arr B (r bit2 = ti7 -> g13 -> q10)
// ---------------------------------------------------------------------------
__global__ __launch_bounds__(256, 2) void qpassP(
    float* __restrict__ sre_st, float* __restrict__ sim_st,
    const float* __restrict__ ws, int layer) {
  __shared__ float2 lds[8192];
  const int t = threadIdx.x;
  const uint32_t blk = blockIdx.x;
  const float* wsU = ws + WS_U;
  float2 c[32];

#pragma unroll
  for (int r = 0; r < 32; ++r) {
    const uint32_t g = gP(blk, IDX_L);
    c[r] = make_float2(sre_st[g], sim_st[g]);
  }

  const int l0 = layer, l1 = layer + 1;
  GATE(0, l0, 9) GATE(1, l0, 8) GATE(2, l0, 7) GATE(3, l0, 6) GATE(4, l0, 5)
  XPOSE(IDX_L, IDX_B)
  GATE(2, l0, 10)
  {
    const uint32_t ti0 = (t & 31) | ((t >> 5) << 10);
    zz_apply<1>(c, ws + WS_W, l0, gP(blk, ti0));
  }
  GATE(2, l1, 10)
  XPOSE(IDX_B, IDX_L)
  GATE(0, l1, 9) GATE(1, l1, 8) GATE(2, l1, 7) GATE(3, l1, 6) GATE(4, l1, 5)

#pragma unroll
  for (int r = 0; r < 32; ++r) {
    const uint32_t g = gP(blk, IDX_L);
    sre_st[g] = c[r].x;
    sim_st[g] = c[r].y;
  }
}

// ---------------------------------------------------------------------------
// Q-type pass (qubits 0..4): single group, all register-local, no LDS.
// arr L: r = ti8..12 -> g19..23 -> q4..0
// ---------------------------------------------------------------------------
__global__ __launch_bounds__(256, 4) void qpassQ(
    float* __restrict__ sre_st, float* __restrict__ sim_st,
    const float* __restrict__ ws, int layer) {
  const int t = threadIdx.x;
  const uint32_t blk = blockIdx.x;
  const float* wsU = ws + WS_U;
  float2 c[32];

#pragma unroll
  for (int r = 0; r < 32; ++r) {
    const uint32_t g = gQ(blk, IDX_L);
    c[r] = make_float2(sre_st[g], sim_st[g]);
  }

  GATE(0, layer, 4) GATE(1, layer, 3) GATE(2, layer, 2) GATE(3, layer, 1)
  GATE(4, layer, 0)

#pragma unroll
  for (int r = 0; r < 32; ++r) {
    const uint32_t g = gQ(blk, IDX_L);
    sre_st[g] = c[r].x;
    sim_st[g] = c[r].y;
  }
}

// ---------------------------------------------------------------------------
extern "C" void kernel_launch(void* const* d_in, const int* in_sizes, int n_in,
                              void* d_out, int out_size, void* d_ws,
                              size_t ws_size, hipStream_t stream) {
  (void)in_sizes; (void)n_in; (void)out_size; (void)ws_size;
  const float* sre = (const float*)d_in[0];
  const float* sim = (const float*)d_in[1];
  const float* Hre = (const float*)d_in[2];
  const float* Him = (const float*)d_in[3];
  const float* th1 = (const float*)d_in[4];
  const float* th2 = (const float*)d_in[5];
  float* ws = (float*)d_ws;
  float* sre_st = (float*)d_out;  // re plane in d_out (2^24 f32)
  float* sim_st = ws + WS_IM;     // im plane in workspace

  const dim3 G(2048), B(256);
  hipLaunchKernelGGL(setup_kernel, dim3(1), dim3(128), 0, stream, Hre, Him,
                     th1, th2, ws);
  hipLaunchKernelGGL((qpassA<0>), G, B, 0, stream, sre, sim, sre_st, sim_st,
                     ws, ws, 0);                              // A0 (+norm)
  hipLaunchKernelGGL(qpassQ, G, B, 0, stream, sre_st, sim_st, ws, 0);  // Q0
  hipLaunchKernelGGL(qpassP, G, B, 0, stream, sre_st, sim_st, ws, 0);  // P0 ZZ0 P1
  hipLaunchKernelGGL(qpassQ, G, B, 0, stream, sre_st, sim_st, ws, 1);  // Q1
  hipLaunchKernelGGL((qpassA<1>), G, B, 0, stream, sre, sim, sre_st, sim_st,
                     ws, ws, 1);                              // A1 ZZ1 A2
  hipLaunchKernelGGL(qpassQ, G, B, 0, stream, sre_st, sim_st, ws, 2);  // Q2
  hipLaunchKernelGGL(qpassP, G, B, 0, stream, sre_st, sim_st, ws, 2);  // P2 ZZ2 P3
  hipLaunchKernelGGL(qpassQ, G, B, 0, stream, sre_st, sim_st, ws, 3);  // Q3
  hipLaunchKernelGGL((qpassA<2>), G, B, 0, stream, sre, sim, sre_st, sim_st,
                     ws, ws, 3);                              // A3 ZZ3 scale
}

// Round 12
// 1026.975 us; speedup vs baseline: 1.8806x; 1.8806x over previous
//
#include <hip/hip_runtime.h>
#include <stdint.h>

// ============================================================================
// 24-qubit simulator, 9 coalesced passes, 12-bit tiles (4096 amps, 32KiB LDS,
// 16 amps/thread) -> 4 blocks/CU (~46% occupancy) to attack latency-bound
// behavior measured at 23% occupancy with 13-bit tiles.
// State SOA: re in d_out (2^24 f32), im in d_ws+WS_IM. Qubit q <-> bit 23-q.
// Tiles: A: g0..11 (q12..23)        blk=g12..23   runs 16KiB
//        P: g{0..5,12..17} (q6..11) blk=g{6..11,18..23} runs 256B
//        Q: g{0..5,18..23} (q0..5)  blk=g6..17    runs 256B
// Schedule: A0 | Q0 | P0.ZZ0.P1 | Q1 | A1.ZZ1.A2 | Q2 | P2.ZZ2.P3 | Q3 | A3.ZZ3.sc
// ============================================================================

#define WS_NORM 0
#define WS_U    8     // 96 matrices * 8 floats
#define WS_W    1024  // 4 layers * 32: w[0..22], [23]=wrap, [24]=S
#define WS_IM   4096  // imag plane: 2^24 floats

__device__ __forceinline__ int swz(int i) { return i ^ ((i >> 4) & 15); }

__device__ __forceinline__ float2 cmul(float2 a, float2 b) {
  return make_float2(a.x * b.x - a.y * b.y, a.x * b.y + a.y * b.x);
}

// apply 2x2 complex gate on local (register) bit P of c[16]
template <int P>
__device__ __forceinline__ void gate(float2 c[16], float2 u00, float2 u01,
                                     float2 u10, float2 u11) {
#pragma unroll
  for (int m = 0; m < 8; ++m) {
    const int r0 = ((m >> P) << (P + 1)) | (m & ((1 << P) - 1));
    const int r1 = r0 | (1 << P);
    float2 a = c[r0], b = c[r1];
    float2 n0, n1;
    n0.x = u00.x * a.x - u00.y * a.y + u01.x * b.x - u01.y * b.y;
    n0.y = u00.x * a.y + u00.y * a.x + u01.x * b.y + u01.y * b.x;
    n1.x = u10.x * a.x - u10.y * a.y + u11.x * b.x - u11.y * b.y;
    n1.y = u10.x * a.y + u10.y * a.x + u11.x * b.y + u11.y * b.x;
    c[r0] = n0;
    c[r1] = n1;
  }
}

// ---------------------------------------------------------------------------
__global__ void setup_kernel(const float* __restrict__ Hre,
                             const float* __restrict__ Him,
                             const float* __restrict__ th1,
                             const float* __restrict__ th2, float* ws) {
  const int id = threadIdx.x;
  if (id < 96) {
    const int l = id / 24, q = id % 24;
    const float* hr = Hre + (l * 24 + q) * 4;
    const float* hi = Him + (l * 24 + q) * 4;
    const float h0 = hi[0] + hi[3];
    const float hz = hi[0] - hi[3];
    const float hx = hi[1] + hi[2];
    const float hy = hr[1] - hr[2];
    const float th = sqrtf(hx * hx + hy * hy + hz * hz);
    const float cth = cosf(th), sth = sinf(th);
    const float sc = (th > 1e-30f) ? sth / th : 1.0f;
    const float2 e = make_float2(cosf(h0), sinf(h0));
    const float2 u00 = cmul(e, make_float2(cth, sc * hz));
    const float2 u01 = cmul(e, make_float2(sc * hy, sc * hx));
    const float2 u10 = cmul(e, make_float2(-sc * hy, sc * hx));
    const float2 u11 = cmul(e, make_float2(cth, -sc * hz));
    float* p = ws + WS_U + (l * 24 + q) * 8;
    p[0] = u00.x; p[1] = u00.y; p[2] = u01.x; p[3] = u01.y;
    p[4] = u10.x; p[5] = u10.y; p[6] = u11.x; p[7] = u11.y;
  } else if (id < 100) {
    const int l = id - 96;
    float w[23];
    for (int k = 0; k < 23; ++k) w[k] = 0.f;
    for (int i = 0; i < 12; ++i) w[22 - 2 * i] += th1[l * 12 + i];
    for (int i = 0; i < 11; ++i) w[21 - 2 * i] += th2[l * 12 + i];
    const float wrap = th2[l * 12 + 11];
    float S = wrap;
    for (int k = 0; k < 23; ++k) S += w[k];
    float* p = ws + WS_W + l * 32;
    for (int k = 0; k < 23; ++k) p[k] = w[k];
    p[23] = wrap;
    p[24] = S;
  } else if (id == 100) {
    ws[WS_NORM] = 0.f;
  }
}

// ---------------------------------------------------------------------------
__device__ __forceinline__ uint32_t gA(uint32_t blk, uint32_t ti) {
  return (blk << 12) | ti;
}
__device__ __forceinline__ uint32_t gP(uint32_t blk, uint32_t ti) {
  return (ti & 0x3F) | ((ti >> 6) << 12) | ((blk & 0x3F) << 6) |
         ((blk >> 6) << 18);
}
__device__ __forceinline__ uint32_t gQ(uint32_t blk, uint32_t ti) {
  return (ti & 0x3F) | ((ti >> 6) << 18) | (blk << 6);
}

#define GATE(P, l, q)                                                      \
  {                                                                        \
    const float* up = wsU + ((l) * 24 + (q)) * 8;                          \
    gate<P>(c, make_float2(up[0], up[1]), make_float2(up[2], up[3]),       \
            make_float2(up[4], up[5]), make_float2(up[6], up[7]));         \
  }

#define XPOSE(CUR, NEW)                                   \
  __syncthreads();                                        \
  _Pragma("unroll") for (int r = 0; r < 16; ++r) {        \
    lds[swz(CUR)] = c[r];                                 \
  }                                                       \
  __syncthreads();                                        \
  _Pragma("unroll") for (int r = 0; r < 16; ++r) {        \
    c[r] = lds[swz(NEW)];                                 \
  }

// arrangements of the 12-bit tile index (t = 8 thread bits, r = 4 reg bits)
#define IDX_L (t + (r << 8))
#define IDX_A ((t << 4) | r)
#define IDX_B ((t & 15) | (r << 4) | ((t >> 4) << 8))

// ---------------------------------------------------------------------------
// ZZ phase: phi(g) = S - 2*sum_k w[k]*y_k - 2*wrap*(b0^b23), y = g^(g>>1).
// TILE 0 (A, arr B): r -> g4..7        window y3..7            wrap fixed
// TILE 1 (P, arr B): r -> g{4,5,12,13} window y{3,4,5,11,12,13} wrap fixed
// ---------------------------------------------------------------------------
template <int TILE>
__device__ __forceinline__ uint32_t zzspread(int r) {
  if constexpr (TILE == 0) return (uint32_t)r << 4;
  else return ((uint32_t)(r & 3) << 4) | ((uint32_t)(r >> 2) << 12);
}

template <int TILE>
__device__ __forceinline__ void zz_apply(float2 c[16],
                                         const float* __restrict__ wsW,
                                         int layer, uint32_t gbase) {
  constexpr uint32_t WMASK = (TILE == 0) ? 0xF8u : 0x3838u;
  const float* w = wsW + layer * 32;
  const uint32_t y0 = gbase ^ (gbase >> 1);
  float phi_b = w[24];
#pragma unroll
  for (int k = 0; k < 23; ++k)
    if (!(WMASK & (1u << k))) phi_b -= 2.f * w[k] * (float)((y0 >> k) & 1);
  phi_b -= 2.f * w[23] * (float)((gbase ^ (gbase >> 23)) & 1);
#pragma unroll
  for (int r = 0; r < 16; ++r) {
    const uint32_t g = gbase | zzspread<TILE>(r);
    const uint32_t y = g ^ (g >> 1);
    float phi = phi_b;
#pragma unroll
    for (int k = 0; k < 23; ++k)
      if (WMASK & (1u << k)) phi -= 2.f * w[k] * (float)((y >> k) & 1);
    float sn, cs;
    __sincosf(phi, &sn, &cs);
    c[r] = cmul(c[r], make_float2(cs, sn));
  }
}

// ---------------------------------------------------------------------------
// A-type pass (qubits 12..23). MODE 0: load input+norm, A_l, store.
// MODE 1: A_l, ZZ_l, A_{l+1}, store.  MODE 2: A_l, ZZ_l, scale, store re.
// arr L: regs g8..11 -> q15..12 | arr A: g0..3 -> q23..20 | arr B: g4..7 -> q19..16
// ---------------------------------------------------------------------------
template <int MODE>
__global__ __launch_bounds__(256, 4) void qpassA(
    const float* __restrict__ in_re, const float* __restrict__ in_im,
    float* __restrict__ sre_st, float* __restrict__ sim_st,
    const float* __restrict__ ws, float* wsn, int layer) {
  __shared__ float2 lds[4096];
  const int t = threadIdx.x;
  const uint32_t blk = blockIdx.x;
  const float* wsU = ws + WS_U;
  float2 c[16];

#pragma unroll
  for (int r = 0; r < 16; ++r) {
    const uint32_t g = gA(blk, IDX_L);
    if (MODE == 0)
      c[r] = make_float2(in_re[g], in_im[g]);
    else
      c[r] = make_float2(sre_st[g], sim_st[g]);
  }

  if (MODE == 0) {
    float ss = 0.f;
#pragma unroll
    for (int r = 0; r < 16; ++r)
      ss = fmaf(c[r].x, c[r].x, fmaf(c[r].y, c[r].y, ss));
    for (int off = 32; off > 0; off >>= 1) ss += __shfl_down(ss, off);
    if ((t & 63) == 0) atomicAdd(wsn + WS_NORM, ss);
  }

  const int l0 = layer;
  GATE(0, l0, 15) GATE(1, l0, 14) GATE(2, l0, 13) GATE(3, l0, 12)
  XPOSE(IDX_L, IDX_A)
  GATE(0, l0, 23) GATE(1, l0, 22) GATE(2, l0, 21) GATE(3, l0, 20)
  XPOSE(IDX_A, IDX_B)
  GATE(0, l0, 19) GATE(1, l0, 18) GATE(2, l0, 17) GATE(3, l0, 16)

  if (MODE != 0) {
    const uint32_t ti0 = (t & 15) | ((t >> 4) << 8);  // IDX_B with r=0
    zz_apply<0>(c, ws + WS_W, l0, gA(blk, ti0));
  }

  if (MODE == 1) {
    const int l1 = layer + 1;
    GATE(0, l1, 19) GATE(1, l1, 18) GATE(2, l1, 17) GATE(3, l1, 16)
    XPOSE(IDX_B, IDX_A)
    GATE(0, l1, 23) GATE(1, l1, 22) GATE(2, l1, 21) GATE(3, l1, 20)
    XPOSE(IDX_A, IDX_L)
    GATE(0, l1, 15) GATE(1, l1, 14) GATE(2, l1, 13) GATE(3, l1, 12)
#pragma unroll
    for (int r = 0; r < 16; ++r) {
      const uint32_t g = gA(blk, IDX_L);
      sre_st[g] = c[r].x;
      sim_st[g] = c[r].y;
    }
  } else {
    float scale = 1.f;
    if (MODE == 2) scale = rsqrtf(wsn[WS_NORM]);
#pragma unroll
    for (int r = 0; r < 16; ++r) {
      const uint32_t g = gA(blk, IDX_B);
      sre_st[g] = c[r].x * scale;
      if (MODE != 2) sim_st[g] = c[r].y;
    }
  }
}

// ---------------------------------------------------------------------------
// P-type pass (qubits 6..11): P_l, ZZ_l, P_{l+1}.
// arr L: regs g14..17 -> q9..6 | arr B: reg bits 2,3 -> g12,13 -> q11,10
// ---------------------------------------------------------------------------
__global__ __launch_bounds__(256, 4) void qpassP(
    float* __restrict__ sre_st, float* __restrict__ sim_st,
    const float* __restrict__ ws, int layer) {
  __shared__ float2 lds[4096];
  const int t = threadIdx.x;
  const uint32_t blk = blockIdx.x;
  const float* wsU = ws + WS_U;
  float2 c[16];

#pragma unroll
  for (int r = 0; r < 16; ++r) {
    const uint32_t g = gP(blk, IDX_L);
    c[r] = make_float2(sre_st[g], sim_st[g]);
  }

  const int l0 = layer, l1 = layer + 1;
  GATE(0, l0, 9) GATE(1, l0, 8) GATE(2, l0, 7) GATE(3, l0, 6)
  XPOSE(IDX_L, IDX_B)
  GATE(2, l0, 11) GATE(3, l0, 10)
  {
    const uint32_t ti0 = (t & 15) | ((t >> 4) << 8);  // IDX_B with r=0
    zz_apply<1>(c, ws + WS_W, l0, gP(blk, ti0));
  }
  GATE(2, l1, 11) GATE(3, l1, 10)
  XPOSE(IDX_B, IDX_L)
  GATE(0, l1, 9) GATE(1, l1, 8) GATE(2, l1, 7) GATE(3, l1, 6)

#pragma unroll
  for (int r = 0; r < 16; ++r) {
    const uint32_t g = gP(blk, IDX_L);
    sre_st[g] = c[r].x;
    sim_st[g] = c[r].y;
  }
}

// ---------------------------------------------------------------------------
// Q-type pass (qubits 0..5), single layer, no ZZ.
// arr L: regs g20..23 -> q3..0 | arr B: reg bits 2,3 -> g18,19 -> q5,4
// ---------------------------------------------------------------------------
__global__ __launch_bounds__(256, 4) void qpassQ(
    float* __restrict__ sre_st, float* __restrict__ sim_st,
    const float* __restrict__ ws, int layer) {
  __shared__ float2 lds[4096];
  const int t = threadIdx.x;
  const uint32_t blk = blockIdx.x;
  const float* wsU = ws + WS_U;
  float2 c[16];

#pragma unroll
  for (int r = 0; r < 16; ++r) {
    const uint32_t g = gQ(blk, IDX_L);
    c[r] = make_float2(sre_st[g], sim_st[g]);
  }

  GATE(0, layer, 3) GATE(1, layer, 2) GATE(2, layer, 1) GATE(3, layer, 0)
  XPOSE(IDX_L, IDX_B)
  GATE(2, layer, 5) GATE(3, layer, 4)

#pragma unroll
  for (int r = 0; r < 16; ++r) {
    const uint32_t g = gQ(blk, IDX_B);
    sre_st[g] = c[r].x;
    sim_st[g] = c[r].y;
  }
}

// ---------------------------------------------------------------------------
extern "C" void kernel_launch(void* const* d_in, const int* in_sizes, int n_in,
                              void* d_out, int out_size, void* d_ws,
                              size_t ws_size, hipStream_t stream) {
  (void)in_sizes; (void)n_in; (void)out_size; (void)ws_size;
  const float* sre = (const float*)d_in[0];
  const float* sim = (const float*)d_in[1];
  const float* Hre = (const float*)d_in[2];
  const float* Him = (const float*)d_in[3];
  const float* th1 = (const float*)d_in[4];
  const float* th2 = (const float*)d_in[5];
  float* ws = (float*)d_ws;
  float* sre_st = (float*)d_out;  // re plane in d_out (2^24 f32)
  float* sim_st = ws + WS_IM;     // im plane in workspace

  const dim3 G(4096), B(256);
  hipLaunchKernelGGL(setup_kernel, dim3(1), dim3(128), 0, stream, Hre, Him,
                     th1, th2, ws);
  hipLaunchKernelGGL((qpassA<0>), G, B, 0, stream, sre, sim, sre_st, sim_st,
                     ws, ws, 0);                              // A0 (+norm)
  hipLaunchKernelGGL(qpassQ, G, B, 0, stream, sre_st, sim_st, ws, 0);  // Q0
  hipLaunchKernelGGL(qpassP, G, B, 0, stream, sre_st, sim_st, ws, 0);  // P0 ZZ0 P1
  hipLaunchKernelGGL(qpassQ, G, B, 0, stream, sre_st, sim_st, ws, 1);  // Q1
  hipLaunchKernelGGL((qpassA<1>), G, B, 0, stream, sre, sim, sre_st, sim_st,
                     ws, ws, 1);                              // A1 ZZ1 A2
  hipLaunchKernelGGL(qpassQ, G, B, 0, stream, sre_st, sim_st, ws, 2);  // Q2
  hipLaunchKernelGGL(qpassP, G, B, 0, stream, sre_st, sim_st, ws, 2);  // P2 ZZ2 P3
  hipLaunchKernelGGL(qpassQ, G, B, 0, stream, sre_st, sim_st, ws, 3);  // Q3
  hipLaunchKernelGGL((qpassA<2>), G, B, 0, stream, sre, sim, sre_st, sim_st,
                     ws, ws, 3);                              // A3 ZZ3 scale
}